// Round 1
// baseline (618.373 us; speedup 1.0000x reference)
//
#include <hip/hip_runtime.h>
#include <math.h>

#define Bb 256
#define Ll 20000
#define WPOOL 3999
#define HEADS 5
#define HDIM 30
#define KSPLIT 8
#define NQKV 450            // 3 proj * 5 heads * 30
#define PSTRIDE (NQKV*1024) // one k-split slice of qkv partials

// workspace layout (float offsets)
#define WS_F 0                          // 360 floats: F[t=0..4][d=0..17][i=0..3]
#define WS_BIAS 368                     // 4 floats
#define WS_X 4096                       // B*WPOOL*4 pooled features, [b][p][i]
#define WS_P (WS_X + Bb*WPOOL*4)        // KSPLIT * 450 * 1024 qkv partials
// total floats: WS_P + 8*450*1024 = 7,785,472  (~31.2 MB)

// -------- K0: build combined conv1*conv2 tap table F and interior bias -----
__global__ void k0_build(const float* __restrict__ w1, const float* __restrict__ b1,
                         const float* __restrict__ w2, const float* __restrict__ b2,
                         float* __restrict__ ws)
{
    int tid = threadIdx.x;
    // F[t][d][i]: contribution of token value t at column offset (d-8) to out2 row i
    for (int idx = tid; idx < 5 * 18 * 4; idx += blockDim.x) {
        int t = idx / 72;
        int d = (idx / 4) % 18;
        int i = idx % 4;
        float acc = 0.f;
        if (t < 4) {
            for (int kh = 0; kh < 4; ++kh) {
                int r = i + kh - 1;            // conv1 output row feeding conv2
                if (r < 0 || r > 3) continue;
                int kh1 = t - r + 1;           // conv1 kernel row selected by one-hot
                if (kh1 < 0 || kh1 > 3) continue;
                int lo = d > 9 ? d - 9 : 0;
                int hi = d < 9 ? d : 9;
                for (int kw1 = lo; kw1 <= hi; ++kw1) {
                    int kw2 = d - kw1;
                    for (int c = 0; c < 5; ++c)
                        acc += w1[(kh1 * 10 + kw1) * 5 + c] * w2[(kh * 10 + kw2) * 5 + c];
                }
            }
        }
        ws[WS_F + idx] = acc;
    }
    if (tid < 4) {
        int i = tid;
        float acc = b2[0];
        for (int kh = 0; kh < 4; ++kh) {
            int r = i + kh - 1;
            if (r < 0 || r > 3) continue;
            for (int kw2 = 0; kw2 < 10; ++kw2)
                for (int c = 0; c < 5; ++c)
                    acc += b1[c] * w2[(kh * 10 + kw2) * 5 + c];
        }
        ws[WS_BIAS + i] = acc;
    }
}

// exact two-stage conv value for boundary columns (conv2 zero-pads conv1 output)
__device__ float slow_out2(const int* __restrict__ tb,
                           const float* __restrict__ w1, const float* __restrict__ b1,
                           const float* __restrict__ w2, float b2v, int i, int w)
{
    float acc = b2v;
    for (int kh = 0; kh < 4; ++kh) {
        int r = i + kh - 1;
        if (r < 0 || r > 3) continue;
        for (int kw2 = 0; kw2 < 10; ++kw2) {
            int wp = w + kw2 - 4;
            if (wp < 0 || wp >= Ll) continue;   // conv2 zero-padding of conv1 output
            float v1[5];
            for (int c = 0; c < 5; ++c) v1[c] = b1[c];
            for (int kw1 = 0; kw1 < 10; ++kw1) {
                int u = wp + kw1 - 4;
                if (u < 0 || u >= Ll) continue; // conv1 zero-padding of one-hot
                int kh1 = tb[u] - r + 1;
                if (kh1 < 0 || kh1 > 3) continue;
                for (int c = 0; c < 5; ++c) v1[c] += w1[(kh1 * 10 + kw1) * 5 + c];
            }
            for (int c = 0; c < 5; ++c) acc += v1[c] * w2[(kh * 10 + kw2) * 5 + c];
        }
    }
    return acc;
}

// -------- K1: fused conv1+conv2 (via F) + maxpool --------------------------
__global__ __launch_bounds__(256) void k1_convpool(const int* __restrict__ tokens,
    const float* __restrict__ w1, const float* __restrict__ b1,
    const float* __restrict__ w2, const float* __restrict__ b2,
    float* __restrict__ ws)
{
    __shared__ float4 Fs[90];       // [t*18+d] -> (i0,i1,i2,i3)
    __shared__ float biasS[4];
    __shared__ int tok[1280];
    __shared__ float4 out2[1280];   // [col] -> 4 rows

    const int tid = threadIdx.x;
    const int b = blockIdx.x >> 4;
    const int chunk = blockIdx.x & 15;
    const int p0 = chunk * 250;
    const int pcnt = min(250, WPOOL - p0);
    const int firstcol = 5 * p0;
    const int colCount = 5 * pcnt + 5;   // columns needed by this chunk's pools
    const int nTok = colCount + 17;

    const float4* Fg = reinterpret_cast<const float4*>(ws + WS_F);
    for (int j = tid; j < 90; j += 256) Fs[j] = Fg[j];
    if (tid < 4) biasS[tid] = ws[WS_BIAS + tid];
    const int* tb = tokens + (size_t)b * Ll;
    for (int j = tid; j < nTok; j += 256) {
        int u = firstcol - 8 + j;
        tok[j] = (u >= 0 && u < Ll) ? tb[u] : 4;   // sentinel 4 -> zero F row
    }
    __syncthreads();

    int base = tid * 5;
    if (base < colCount) {
        if (base + 5 <= colCount) {
            int tk[22];
#pragma unroll
            for (int j = 0; j < 22; ++j) tk[j] = tok[base + j];
#pragma unroll
            for (int u = 0; u < 5; ++u) {
                float a0 = biasS[0], a1 = biasS[1], a2 = biasS[2], a3 = biasS[3];
#pragma unroll
                for (int d = 0; d < 18; ++d) {
                    float4 f = Fs[tk[u + d] * 18 + d];
                    a0 += f.x; a1 += f.y; a2 += f.z; a3 += f.w;
                }
                out2[base + u] = make_float4(a0, a1, a2, a3);
            }
        } else {
            for (int cc = base; cc < colCount; ++cc) {
                float a0 = biasS[0], a1 = biasS[1], a2 = biasS[2], a3 = biasS[3];
                for (int d = 0; d < 18; ++d) {
                    float4 f = Fs[tok[cc + d] * 18 + d];
                    a0 += f.x; a1 += f.y; a2 += f.z; a3 += f.w;
                }
                out2[cc] = make_float4(a0, a1, a2, a3);
            }
        }
    }
    __syncthreads();

    // boundary columns where the F-formula is invalid (9 per batch row)
    if (chunk == 0 && tid < 16) {
        int i = tid & 3, w = tid >> 2;          // w = 0..3
        reinterpret_cast<float*>(out2)[w * 4 + i] = slow_out2(tb, w1, b1, w2, b2[0], i, w);
    }
    if (chunk == 15 && tid < 20) {
        int i = tid & 3, w = Ll - 5 + (tid >> 2); // w = 19995..19999
        reinterpret_cast<float*>(out2)[(w - firstcol) * 4 + i] =
            slow_out2(tb, w1, b1, w2, b2[0], i, w);
    }
    __syncthreads();

    if (tid < pcnt) {
        float4 m = out2[5 * tid];
#pragma unroll
        for (int j = 1; j < 10; ++j) {
            float4 v = out2[5 * tid + j];
            m.x = fmaxf(m.x, v.x); m.y = fmaxf(m.y, v.y);
            m.z = fmaxf(m.z, v.z); m.w = fmaxf(m.w, v.w);
        }
        reinterpret_cast<float4*>(ws + WS_X)[(size_t)b * WPOOL + p0 + tid] = m;
    }
}

// -------- K2: qkv projections, K-split GEMM into partial buffers -----------
__global__ __launch_bounds__(256) void k2_qkv(const float* __restrict__ Wq,
    const float* __restrict__ Wk, const float* __restrict__ Wv,
    float* __restrict__ ws)
{
    int gid = blockIdx.x * 256 + threadIdx.x;
    int ks  = gid / (256 * NQKV);
    int rem = gid - ks * (256 * NQKV);
    int bq  = rem / NQKV;          // batch index
    int n   = rem - bq * NQKV;     // (proj, head, e)
    int proj = n / 150;
    int r2 = n - proj * 150;
    int hh = r2 / 30;
    int e  = r2 - hh * 30;
    const float* Wm = (proj == 0) ? Wq : ((proj == 1) ? Wk : Wv);
    const float* wcol = Wm + (size_t)hh * WPOOL * 30 + e;
    const float4* xrow = reinterpret_cast<const float4*>(ws + WS_X) + (size_t)bq * WPOOL;
    int k0 = ks * 500;
    int k1 = min(k0 + 500, WPOOL);
    float a0 = 0.f, a1 = 0.f, a2 = 0.f, a3 = 0.f;
#pragma unroll 4
    for (int k = k0; k < k1; ++k) {
        float wv = wcol[(size_t)k * 30];
        float4 xv = xrow[k];            // all 4 sequence rows of this batch
        a0 = fmaf(xv.x, wv, a0); a1 = fmaf(xv.y, wv, a1);
        a2 = fmaf(xv.z, wv, a2); a3 = fmaf(xv.w, wv, a3);
    }
    float* P = ws + WS_P + (size_t)ks * PSTRIDE + (size_t)n * 1024 + bq * 4;
    P[0] = a0; P[1] = a1; P[2] = a2; P[3] = a3;
}

// -------- K3: attention (S=4 causal) + Wo + dense head, one block per b ----
__global__ __launch_bounds__(256) void k3_attn(const float* __restrict__ Wo,
    const float* __restrict__ d1w, const float* __restrict__ d1b,
    const float* __restrict__ d2w, const float* __restrict__ d2b,
    const float* __restrict__ d3w, const float* __restrict__ d3b,
    const float* __restrict__ ws, float* __restrict__ out)
{
    __shared__ float Qs[5][4][30], Ks2[5][4][30], Vs[5][4][30];
    __shared__ float sc[5][4][4];
    __shared__ float ob[4][150];
    __shared__ float hb[120], h1[10], h2[10];
    const int tid = threadIdx.x;
    const int b = blockIdx.x;
    const float* P = ws + WS_P;

    for (int idx = tid; idx < 1800; idx += 256) {
        int n = idx % NQKV;
        int s = idx / NQKV;
        float val = 0.f;
        for (int ks = 0; ks < KSPLIT; ++ks)
            val += P[(size_t)ks * PSTRIDE + (size_t)n * 1024 + b * 4 + s];
        int proj = n / 150, hh = (n % 150) / 30, e = n % 30;
        if (proj == 0)      Qs[hh][s][e] = val;
        else if (proj == 1) Ks2[hh][s][e] = val;
        else                Vs[hh][s][e] = val;
    }
    __syncthreads();

    if (tid < 80) {
        int hh = tid >> 4, s = (tid >> 2) & 3, t = tid & 3;
        float a = 0.f;
        if (t <= s) {
            for (int e = 0; e < 30; ++e) a += Qs[hh][s][e] * Ks2[hh][t][e];
            a *= (1.0f / sqrtf(30.0f));
        }
        sc[hh][s][t] = a;
    }
    __syncthreads();

    if (tid < 20) {
        int hh = tid / 4, s = tid % 4;
        float m = -1e30f;
        for (int t = 0; t <= s; ++t) m = fmaxf(m, sc[hh][s][t]);
        float ex[4]; float den = 0.f;
        for (int t = 0; t <= s; ++t) { ex[t] = expf(sc[hh][s][t] - m); den += ex[t]; }
        for (int t = 0; t < 4; ++t) sc[hh][s][t] = (t <= s) ? ex[t] / den : 0.f;
    }
    __syncthreads();

    for (int idx = tid; idx < 600; idx += 256) {
        int s = idx / 150, j = idx % 150, hh = j / 30, e = j % 30;
        float a = 0.f;
        for (int t = 0; t < 4; ++t) a += sc[hh][s][t] * Vs[hh][t][e];
        ob[s][j] = a;
    }
    __syncthreads();

    if (tid < 120) {
        int s = tid / 30, e2 = tid % 30;
        float a = 0.f;
        for (int j = 0; j < 150; ++j) a += ob[s][j] * Wo[j * 30 + e2];
        hb[s * 30 + e2] = a;
    }
    __syncthreads();

    if (tid < 10) {
        float a = d1b[tid];
        for (int i = 0; i < 120; ++i) a += hb[i] * d1w[i * 10 + tid];
        h1[tid] = a > 0.f ? a : 0.2f * a;
    }
    __syncthreads();
    if (tid < 10) {
        float a = d2b[tid];
        for (int i = 0; i < 10; ++i) a += h1[i] * d2w[i * 10 + tid];
        h2[tid] = a > 0.f ? a : 0.2f * a;
    }
    __syncthreads();
    if (tid == 0) {
        float a = d3b[0];
        for (int i = 0; i < 10; ++i) a += h2[i] * d3w[i];
        out[b] = 1.f / (1.f + expf(-a));
    }
}

extern "C" void kernel_launch(void* const* d_in, const int* in_sizes, int n_in,
                              void* d_out, int out_size, void* d_ws, size_t ws_size,
                              hipStream_t stream)
{
    const int*   tokens = (const int*)d_in[0];
    const float* c1w = (const float*)d_in[1];
    const float* c1b = (const float*)d_in[2];
    const float* c2w = (const float*)d_in[3];
    const float* c2b = (const float*)d_in[4];
    const float* Wq  = (const float*)d_in[5];
    const float* Wk  = (const float*)d_in[6];
    const float* Wv  = (const float*)d_in[7];
    const float* Wo  = (const float*)d_in[8];
    const float* d1w = (const float*)d_in[9];
    const float* d1b = (const float*)d_in[10];
    const float* d2w = (const float*)d_in[11];
    const float* d2b = (const float*)d_in[12];
    const float* d3w = (const float*)d_in[13];
    const float* d3b = (const float*)d_in[14];
    float* ws = (float*)d_ws;
    float* out = (float*)d_out;

    k0_build<<<1, 256, 0, stream>>>(c1w, c1b, c2w, c2b, ws);
    k1_convpool<<<Bb * 16, 256, 0, stream>>>(tokens, c1w, c1b, c2w, c2b, ws);
    k2_qkv<<<(KSPLIT * 256 * NQKV) / 256, 256, 0, stream>>>(Wq, Wk, Wv, ws);
    k3_attn<<<Bb, 256, 0, stream>>>(Wo, d1w, d1b, d2w, d2b, d3w, d3b, ws, out);
}

// Round 2
// 483.579 us; speedup vs baseline: 1.2787x; 1.2787x over previous
//
#include <hip/hip_runtime.h>
#include <math.h>

#define Bb 256
#define Ll 20000
#define WPOOL 3999
#define HEADS 5
#define HDIM 30
#define KSPLIT 8
#define NQKV 450            // 3 proj * 5 heads * 30
#define PSTRIDE (NQKV*1024) // one k-split slice of qkv partials
#define BQT 2               // batches per k2 block

// workspace layout (float offsets)
#define WS_F 0                          // 360 floats: F[t=0..4][d=0..17][i=0..3]
#define WS_BIAS 368                     // 4 floats
#define WS_X 4096                       // B*WPOOL*4 pooled features, [b][p][i]
#define WS_P (WS_X + Bb*WPOOL*4)        // KSPLIT * 450 * 1024 qkv partials
// total floats: WS_P + 8*450*1024 = 7,785,472  (~31.2 MB)

// -------- K0: build combined conv1*conv2 tap table F and interior bias -----
__global__ void k0_build(const float* __restrict__ w1, const float* __restrict__ b1,
                         const float* __restrict__ w2, const float* __restrict__ b2,
                         float* __restrict__ ws)
{
    int tid = threadIdx.x;
    for (int idx = tid; idx < 5 * 18 * 4; idx += blockDim.x) {
        int t = idx / 72;
        int d = (idx / 4) % 18;
        int i = idx % 4;
        float acc = 0.f;
        if (t < 4) {
            for (int kh = 0; kh < 4; ++kh) {
                int r = i + kh - 1;
                if (r < 0 || r > 3) continue;
                int kh1 = t - r + 1;
                if (kh1 < 0 || kh1 > 3) continue;
                int lo = d > 9 ? d - 9 : 0;
                int hi = d < 9 ? d : 9;
                for (int kw1 = lo; kw1 <= hi; ++kw1) {
                    int kw2 = d - kw1;
                    for (int c = 0; c < 5; ++c)
                        acc += w1[(kh1 * 10 + kw1) * 5 + c] * w2[(kh * 10 + kw2) * 5 + c];
                }
            }
        }
        ws[WS_F + idx] = acc;
    }
    if (tid < 4) {
        int i = tid;
        float acc = b2[0];
        for (int kh = 0; kh < 4; ++kh) {
            int r = i + kh - 1;
            if (r < 0 || r > 3) continue;
            for (int kw2 = 0; kw2 < 10; ++kw2)
                for (int c = 0; c < 5; ++c)
                    acc += b1[c] * w2[(kh * 10 + kw2) * 5 + c];
        }
        ws[WS_BIAS + i] = acc;
    }
}

// exact two-stage conv value for boundary columns
__device__ float slow_out2(const int* __restrict__ tb,
                           const float* __restrict__ w1, const float* __restrict__ b1,
                           const float* __restrict__ w2, float b2v, int i, int w)
{
    float acc = b2v;
    for (int kh = 0; kh < 4; ++kh) {
        int r = i + kh - 1;
        if (r < 0 || r > 3) continue;
        for (int kw2 = 0; kw2 < 10; ++kw2) {
            int wp = w + kw2 - 4;
            if (wp < 0 || wp >= Ll) continue;
            float v1[5];
            for (int c = 0; c < 5; ++c) v1[c] = b1[c];
            for (int kw1 = 0; kw1 < 10; ++kw1) {
                int u = wp + kw1 - 4;
                if (u < 0 || u >= Ll) continue;
                int kh1 = tb[u] - r + 1;
                if (kh1 < 0 || kh1 > 3) continue;
                for (int c = 0; c < 5; ++c) v1[c] += w1[(kh1 * 10 + kw1) * 5 + c];
            }
            for (int c = 0; c < 5; ++c) acc += v1[c] * w2[(kh * 10 + kw2) * 5 + c];
        }
    }
    return acc;
}

// -------- K1: fused conv1+conv2 (via F) + maxpool --------------------------
__global__ __launch_bounds__(256) void k1_convpool(const int* __restrict__ tokens,
    const float* __restrict__ w1, const float* __restrict__ b1,
    const float* __restrict__ w2, const float* __restrict__ b2,
    float* __restrict__ ws)
{
    __shared__ float4 Fs[90];
    __shared__ float biasS[4];
    __shared__ int tok[1280];
    __shared__ float4 out2[1280];

    const int tid = threadIdx.x;
    const int b = blockIdx.x >> 4;
    const int chunk = blockIdx.x & 15;
    const int p0 = chunk * 250;
    const int pcnt = min(250, WPOOL - p0);
    const int firstcol = 5 * p0;
    const int colCount = 5 * pcnt + 5;
    const int nTok = colCount + 17;

    const float4* Fg = reinterpret_cast<const float4*>(ws + WS_F);
    for (int j = tid; j < 90; j += 256) Fs[j] = Fg[j];
    if (tid < 4) biasS[tid] = ws[WS_BIAS + tid];
    const int* tb = tokens + (size_t)b * Ll;
    for (int j = tid; j < nTok; j += 256) {
        int u = firstcol - 8 + j;
        tok[j] = (u >= 0 && u < Ll) ? tb[u] : 4;
    }
    __syncthreads();

    int base = tid * 5;
    if (base < colCount) {
        if (base + 5 <= colCount) {
            int tk[22];
#pragma unroll
            for (int j = 0; j < 22; ++j) tk[j] = tok[base + j];
#pragma unroll
            for (int u = 0; u < 5; ++u) {
                float a0 = biasS[0], a1 = biasS[1], a2 = biasS[2], a3 = biasS[3];
#pragma unroll
                for (int d = 0; d < 18; ++d) {
                    float4 f = Fs[tk[u + d] * 18 + d];
                    a0 += f.x; a1 += f.y; a2 += f.z; a3 += f.w;
                }
                out2[base + u] = make_float4(a0, a1, a2, a3);
            }
        } else {
            for (int cc = base; cc < colCount; ++cc) {
                float a0 = biasS[0], a1 = biasS[1], a2 = biasS[2], a3 = biasS[3];
                for (int d = 0; d < 18; ++d) {
                    float4 f = Fs[tok[cc + d] * 18 + d];
                    a0 += f.x; a1 += f.y; a2 += f.z; a3 += f.w;
                }
                out2[cc] = make_float4(a0, a1, a2, a3);
            }
        }
    }
    __syncthreads();

    if (chunk == 0 && tid < 16) {
        int i = tid & 3, w = tid >> 2;
        reinterpret_cast<float*>(out2)[w * 4 + i] = slow_out2(tb, w1, b1, w2, b2[0], i, w);
    }
    if (chunk == 15 && tid < 20) {
        int i = tid & 3, w = Ll - 5 + (tid >> 2);
        reinterpret_cast<float*>(out2)[(w - firstcol) * 4 + i] =
            slow_out2(tb, w1, b1, w2, b2[0], i, w);
    }
    __syncthreads();

    if (tid < pcnt) {
        float4 m = out2[5 * tid];
#pragma unroll
        for (int j = 1; j < 10; ++j) {
            float4 v = out2[5 * tid + j];
            m.x = fmaxf(m.x, v.x); m.y = fmaxf(m.y, v.y);
            m.z = fmaxf(m.z, v.z); m.w = fmaxf(m.w, v.w);
        }
        reinterpret_cast<float4*>(ws + WS_X)[(size_t)b * WPOOL + p0 + tid] = m;
    }
}

// -------- K2 v2: register-blocked qkv GEMM ----------------------------------
// grid = (B/BQT) * KSPLIT blocks, 128 threads.
// Block: batches [bq0, bq0+BQT), k-slice [k0, k0+500). x staged in LDS
// (broadcast reads). Thread owns 4 output cols (e-quad) or 2 (e-pair):
// per (proj,head): 7 quads (e0=0,4,..,24) + 1 pair (e0=28) = 120 units.
// 32 fma per k per thread vs ~48 bytes -> compute-bound.
__global__ __launch_bounds__(128) void k2_qkv(const float* __restrict__ Wq,
    const float* __restrict__ Wk, const float* __restrict__ Wv,
    float* __restrict__ ws)
{
    __shared__ float4 xs[BQT][500];
    const int tid = threadIdx.x;
    const int ks = blockIdx.x & 7;
    const int bt = blockIdx.x >> 3;
    const int bq0 = bt * BQT;
    const int k0 = ks * 500;
    const int kn = min(500, WPOOL - k0);

    const float4* xg = reinterpret_cast<const float4*>(ws + WS_X);
#pragma unroll
    for (int b = 0; b < BQT; ++b)
        for (int kk = tid; kk < kn; kk += 128)
            xs[b][kk] = xg[(size_t)(bq0 + b) * WPOOL + k0 + kk];
    __syncthreads();

    const bool active = tid < 120;
    const int ph = tid >> 3, j = tid & 7;
    const int proj = ph / 5, hh = ph % 5;
    const int e0 = (j < 7) ? 4 * j : 28;
    const int nw = (j < 7) ? 4 : 2;
    const float* Wm = (proj == 0) ? Wq : ((proj == 1) ? Wk : Wv);
    const float* wbase = Wm + (size_t)hh * WPOOL * 30 + (size_t)k0 * 30 + e0;

    float acc[BQT][4][4] = {};
    if (active) {
        const bool quad = (nw == 4);
#pragma unroll 2
        for (int kk = 0; kk < kn; ++kk) {
            const float* wp = wbase + (size_t)kk * 30;
            float w0 = wp[0], w1 = wp[1];
            float w2 = 0.f, w3 = 0.f;
            if (quad) { w2 = wp[2]; w3 = wp[3]; }
            float4 xa = xs[0][kk];
            float4 xb = xs[1][kk];
            acc[0][0][0] = fmaf(xa.x, w0, acc[0][0][0]);
            acc[0][1][0] = fmaf(xa.y, w0, acc[0][1][0]);
            acc[0][2][0] = fmaf(xa.z, w0, acc[0][2][0]);
            acc[0][3][0] = fmaf(xa.w, w0, acc[0][3][0]);
            acc[0][0][1] = fmaf(xa.x, w1, acc[0][0][1]);
            acc[0][1][1] = fmaf(xa.y, w1, acc[0][1][1]);
            acc[0][2][1] = fmaf(xa.z, w1, acc[0][2][1]);
            acc[0][3][1] = fmaf(xa.w, w1, acc[0][3][1]);
            acc[0][0][2] = fmaf(xa.x, w2, acc[0][0][2]);
            acc[0][1][2] = fmaf(xa.y, w2, acc[0][1][2]);
            acc[0][2][2] = fmaf(xa.z, w2, acc[0][2][2]);
            acc[0][3][2] = fmaf(xa.w, w2, acc[0][3][2]);
            acc[0][0][3] = fmaf(xa.x, w3, acc[0][0][3]);
            acc[0][1][3] = fmaf(xa.y, w3, acc[0][1][3]);
            acc[0][2][3] = fmaf(xa.z, w3, acc[0][2][3]);
            acc[0][3][3] = fmaf(xa.w, w3, acc[0][3][3]);
            acc[1][0][0] = fmaf(xb.x, w0, acc[1][0][0]);
            acc[1][1][0] = fmaf(xb.y, w0, acc[1][1][0]);
            acc[1][2][0] = fmaf(xb.z, w0, acc[1][2][0]);
            acc[1][3][0] = fmaf(xb.w, w0, acc[1][3][0]);
            acc[1][0][1] = fmaf(xb.x, w1, acc[1][0][1]);
            acc[1][1][1] = fmaf(xb.y, w1, acc[1][1][1]);
            acc[1][2][1] = fmaf(xb.z, w1, acc[1][2][1]);
            acc[1][3][1] = fmaf(xb.w, w1, acc[1][3][1]);
            acc[1][0][2] = fmaf(xb.x, w2, acc[1][0][2]);
            acc[1][1][2] = fmaf(xb.y, w2, acc[1][1][2]);
            acc[1][2][2] = fmaf(xb.z, w2, acc[1][2][2]);
            acc[1][3][2] = fmaf(xb.w, w2, acc[1][3][2]);
            acc[1][0][3] = fmaf(xb.x, w3, acc[1][0][3]);
            acc[1][1][3] = fmaf(xb.y, w3, acc[1][1][3]);
            acc[1][2][3] = fmaf(xb.z, w3, acc[1][2][3]);
            acc[1][3][3] = fmaf(xb.w, w3, acc[1][3][3]);
        }

        float* Pb = ws + WS_P + (size_t)ks * PSTRIDE;
#pragma unroll
        for (int jj = 0; jj < 4; ++jj) {
            if (jj >= nw) break;
            int n = proj * 150 + hh * 30 + e0 + jj;
#pragma unroll
            for (int b = 0; b < BQT; ++b) {
                float4 v = make_float4(acc[b][0][jj], acc[b][1][jj],
                                       acc[b][2][jj], acc[b][3][jj]);
                reinterpret_cast<float4*>(Pb + (size_t)n * 1024 + (bq0 + b) * 4)[0] = v;
            }
        }
    }
}

// -------- K3: attention (S=4 causal) + Wo + dense head ---------------------
__global__ __launch_bounds__(256) void k3_attn(const float* __restrict__ Wo,
    const float* __restrict__ d1w, const float* __restrict__ d1b,
    const float* __restrict__ d2w, const float* __restrict__ d2b,
    const float* __restrict__ d3w, const float* __restrict__ d3b,
    const float* __restrict__ ws, float* __restrict__ out)
{
    __shared__ float Qs[5][4][30], Ks2[5][4][30], Vs[5][4][30];
    __shared__ float sc[5][4][4];
    __shared__ float ob[4][150];
    __shared__ float hb[120], h1[10], h2[10];
    const int tid = threadIdx.x;
    const int b = blockIdx.x;
    const float* P = ws + WS_P;

    for (int idx = tid; idx < 1800; idx += 256) {
        int n = idx % NQKV;
        int s = idx / NQKV;
        float val = 0.f;
        for (int ks = 0; ks < KSPLIT; ++ks)
            val += P[(size_t)ks * PSTRIDE + (size_t)n * 1024 + b * 4 + s];
        int proj = n / 150, hh = (n % 150) / 30, e = n % 30;
        if (proj == 0)      Qs[hh][s][e] = val;
        else if (proj == 1) Ks2[hh][s][e] = val;
        else                Vs[hh][s][e] = val;
    }
    __syncthreads();

    if (tid < 80) {
        int hh = tid >> 4, s = (tid >> 2) & 3, t = tid & 3;
        float a = 0.f;
        if (t <= s) {
            for (int e = 0; e < 30; ++e) a += Qs[hh][s][e] * Ks2[hh][t][e];
            a *= (1.0f / sqrtf(30.0f));
        }
        sc[hh][s][t] = a;
    }
    __syncthreads();

    if (tid < 20) {
        int hh = tid / 4, s = tid % 4;
        float m = -1e30f;
        for (int t = 0; t <= s; ++t) m = fmaxf(m, sc[hh][s][t]);
        float ex[4]; float den = 0.f;
        for (int t = 0; t <= s; ++t) { ex[t] = expf(sc[hh][s][t] - m); den += ex[t]; }
        for (int t = 0; t < 4; ++t) sc[hh][s][t] = (t <= s) ? ex[t] / den : 0.f;
    }
    __syncthreads();

    for (int idx = tid; idx < 600; idx += 256) {
        int s = idx / 150, j = idx % 150, hh = j / 30, e = j % 30;
        float a = 0.f;
        for (int t = 0; t < 4; ++t) a += sc[hh][s][t] * Vs[hh][t][e];
        ob[s][j] = a;
    }
    __syncthreads();

    if (tid < 120) {
        int s = tid / 30, e2 = tid % 30;
        float a = 0.f;
        for (int j = 0; j < 150; ++j) a += ob[s][j] * Wo[j * 30 + e2];
        hb[s * 30 + e2] = a;
    }
    __syncthreads();

    if (tid < 10) {
        float a = d1b[tid];
        for (int i = 0; i < 120; ++i) a += hb[i] * d1w[i * 10 + tid];
        h1[tid] = a > 0.f ? a : 0.2f * a;
    }
    __syncthreads();
    if (tid < 10) {
        float a = d2b[tid];
        for (int i = 0; i < 10; ++i) a += h1[i] * d2w[i * 10 + tid];
        h2[tid] = a > 0.f ? a : 0.2f * a;
    }
    __syncthreads();
    if (tid == 0) {
        float a = d3b[0];
        for (int i = 0; i < 10; ++i) a += h2[i] * d3w[i];
        out[b] = 1.f / (1.f + expf(-a));
    }
}

extern "C" void kernel_launch(void* const* d_in, const int* in_sizes, int n_in,
                              void* d_out, int out_size, void* d_ws, size_t ws_size,
                              hipStream_t stream)
{
    const int*   tokens = (const int*)d_in[0];
    const float* c1w = (const float*)d_in[1];
    const float* c1b = (const float*)d_in[2];
    const float* c2w = (const float*)d_in[3];
    const float* c2b = (const float*)d_in[4];
    const float* Wq  = (const float*)d_in[5];
    const float* Wk  = (const float*)d_in[6];
    const float* Wv  = (const float*)d_in[7];
    const float* Wo  = (const float*)d_in[8];
    const float* d1w = (const float*)d_in[9];
    const float* d1b = (const float*)d_in[10];
    const float* d2w = (const float*)d_in[11];
    const float* d2b = (const float*)d_in[12];
    const float* d3w = (const float*)d_in[13];
    const float* d3b = (const float*)d_in[14];
    float* ws = (float*)d_ws;
    float* out = (float*)d_out;

    k0_build<<<1, 256, 0, stream>>>(c1w, c1b, c2w, c2b, ws);
    k1_convpool<<<Bb * 16, 256, 0, stream>>>(tokens, c1w, c1b, c2w, c2b, ws);
    k2_qkv<<<(Bb / BQT) * KSPLIT, 128, 0, stream>>>(Wq, Wk, Wv, ws);
    k3_attn<<<Bb, 256, 0, stream>>>(Wo, d1w, d1b, d2w, d2b, d3w, d3b, ws, out);
}

// Round 3
// 344.132 us; speedup vs baseline: 1.7969x; 1.4052x over previous
//
#include <hip/hip_runtime.h>
#include <math.h>

#define Bb 256
#define Ll 20000
#define WPOOL 3999
#define HEADS 5
#define HDIM 30
#define KSPLIT 8
#define NQKV 450            // 3 proj * 5 heads * 30
#define PSTRIDE (NQKV*1024) // one k-split slice: 256 b * 4 s * 450 n floats
#define BQT 2               // batches per k2 block

// workspace layout (float offsets)
#define WS_F 0                          // 360 floats: F[t=0..4][d=0..17][i=0..3]
#define WS_BIAS 368                     // 4 floats
#define WS_X 4096                       // B*WPOOL*4 pooled features, [b][p][i]
#define WS_P (WS_X + Bb*WPOOL*4)        // KSPLIT slices of qkv partials
// total floats: WS_P + 8*460800 = 7,785,472  (~31.1 MB)

// -------- K0: build combined conv1*conv2 tap table F and interior bias -----
__global__ void k0_build(const float* __restrict__ w1, const float* __restrict__ b1,
                         const float* __restrict__ w2, const float* __restrict__ b2,
                         float* __restrict__ ws)
{
    int tid = threadIdx.x;
    for (int idx = tid; idx < 5 * 18 * 4; idx += blockDim.x) {
        int t = idx / 72;
        int d = (idx / 4) % 18;
        int i = idx % 4;
        float acc = 0.f;
        if (t < 4) {
            for (int kh = 0; kh < 4; ++kh) {
                int r = i + kh - 1;
                if (r < 0 || r > 3) continue;
                int kh1 = t - r + 1;
                if (kh1 < 0 || kh1 > 3) continue;
                int lo = d > 9 ? d - 9 : 0;
                int hi = d < 9 ? d : 9;
                for (int kw1 = lo; kw1 <= hi; ++kw1) {
                    int kw2 = d - kw1;
                    for (int c = 0; c < 5; ++c)
                        acc += w1[(kh1 * 10 + kw1) * 5 + c] * w2[(kh * 10 + kw2) * 5 + c];
                }
            }
        }
        ws[WS_F + idx] = acc;
    }
    if (tid < 4) {
        int i = tid;
        float acc = b2[0];
        for (int kh = 0; kh < 4; ++kh) {
            int r = i + kh - 1;
            if (r < 0 || r > 3) continue;
            for (int kw2 = 0; kw2 < 10; ++kw2)
                for (int c = 0; c < 5; ++c)
                    acc += b1[c] * w2[(kh * 10 + kw2) * 5 + c];
        }
        ws[WS_BIAS + i] = acc;
    }
}

// exact two-stage conv value for boundary columns
__device__ float slow_out2(const int* __restrict__ tb,
                           const float* __restrict__ w1, const float* __restrict__ b1,
                           const float* __restrict__ w2, float b2v, int i, int w)
{
    float acc = b2v;
    for (int kh = 0; kh < 4; ++kh) {
        int r = i + kh - 1;
        if (r < 0 || r > 3) continue;
        for (int kw2 = 0; kw2 < 10; ++kw2) {
            int wp = w + kw2 - 4;
            if (wp < 0 || wp >= Ll) continue;
            float v1[5];
            for (int c = 0; c < 5; ++c) v1[c] = b1[c];
            for (int kw1 = 0; kw1 < 10; ++kw1) {
                int u = wp + kw1 - 4;
                if (u < 0 || u >= Ll) continue;
                int kh1 = tb[u] - r + 1;
                if (kh1 < 0 || kh1 > 3) continue;
                for (int c = 0; c < 5; ++c) v1[c] += w1[(kh1 * 10 + kw1) * 5 + c];
            }
            for (int c = 0; c < 5; ++c) acc += v1[c] * w2[(kh * 10 + kw2) * 5 + c];
        }
    }
    return acc;
}

// -------- K1: fused conv1+conv2 (via F) + maxpool --------------------------
__global__ __launch_bounds__(256) void k1_convpool(const int* __restrict__ tokens,
    const float* __restrict__ w1, const float* __restrict__ b1,
    const float* __restrict__ w2, const float* __restrict__ b2,
    float* __restrict__ ws)
{
    __shared__ float4 Fs[90];
    __shared__ float biasS[4];
    __shared__ int tok[1280];
    __shared__ float4 out2[1280];

    const int tid = threadIdx.x;
    const int b = blockIdx.x >> 4;
    const int chunk = blockIdx.x & 15;
    const int p0 = chunk * 250;
    const int pcnt = min(250, WPOOL - p0);
    const int firstcol = 5 * p0;
    const int colCount = 5 * pcnt + 5;
    const int nTok = colCount + 17;

    const float4* Fg = reinterpret_cast<const float4*>(ws + WS_F);
    for (int j = tid; j < 90; j += 256) Fs[j] = Fg[j];
    if (tid < 4) biasS[tid] = ws[WS_BIAS + tid];
    const int* tb = tokens + (size_t)b * Ll;
    for (int j = tid; j < nTok; j += 256) {
        int u = firstcol - 8 + j;
        tok[j] = (u >= 0 && u < Ll) ? tb[u] : 4;
    }
    __syncthreads();

    int base = tid * 5;
    if (base < colCount) {
        if (base + 5 <= colCount) {
            int tk[22];
#pragma unroll
            for (int j = 0; j < 22; ++j) tk[j] = tok[base + j];
#pragma unroll
            for (int u = 0; u < 5; ++u) {
                float a0 = biasS[0], a1 = biasS[1], a2 = biasS[2], a3 = biasS[3];
#pragma unroll
                for (int d = 0; d < 18; ++d) {
                    float4 f = Fs[tk[u + d] * 18 + d];
                    a0 += f.x; a1 += f.y; a2 += f.z; a3 += f.w;
                }
                out2[base + u] = make_float4(a0, a1, a2, a3);
            }
        } else {
            for (int cc = base; cc < colCount; ++cc) {
                float a0 = biasS[0], a1 = biasS[1], a2 = biasS[2], a3 = biasS[3];
                for (int d = 0; d < 18; ++d) {
                    float4 f = Fs[tok[cc + d] * 18 + d];
                    a0 += f.x; a1 += f.y; a2 += f.z; a3 += f.w;
                }
                out2[cc] = make_float4(a0, a1, a2, a3);
            }
        }
    }
    __syncthreads();

    if (chunk == 0 && tid < 16) {
        int i = tid & 3, w = tid >> 2;
        reinterpret_cast<float*>(out2)[w * 4 + i] = slow_out2(tb, w1, b1, w2, b2[0], i, w);
    }
    if (chunk == 15 && tid < 20) {
        int i = tid & 3, w = Ll - 5 + (tid >> 2);
        reinterpret_cast<float*>(out2)[(w - firstcol) * 4 + i] =
            slow_out2(tb, w1, b1, w2, b2[0], i, w);
    }
    __syncthreads();

    if (tid < pcnt) {
        float4 m = out2[5 * tid];
#pragma unroll
        for (int j = 1; j < 10; ++j) {
            float4 v = out2[5 * tid + j];
            m.x = fmaxf(m.x, v.x); m.y = fmaxf(m.y, v.y);
            m.z = fmaxf(m.z, v.z); m.w = fmaxf(m.w, v.w);
        }
        reinterpret_cast<float4*>(ws + WS_X)[(size_t)b * WPOOL + p0 + tid] = m;
    }
}

// -------- K2 v3: register-blocked qkv GEMM, 4-deep W prefetch ---------------
__global__ __launch_bounds__(128) void k2_qkv(const float* __restrict__ Wq,
    const float* __restrict__ Wk, const float* __restrict__ Wv,
    float* __restrict__ ws)
{
    __shared__ float4 xs[BQT][500];
    const int tid = threadIdx.x;
    const int ks = blockIdx.x & 7;
    const int bt = blockIdx.x >> 3;
    const int bq0 = bt * BQT;
    const int k0 = ks * 500;
    const int kn = min(500, WPOOL - k0);

    const float4* xg = reinterpret_cast<const float4*>(ws + WS_X);
#pragma unroll
    for (int b = 0; b < BQT; ++b)
        for (int kk = tid; kk < kn; kk += 128)
            xs[b][kk] = xg[(size_t)(bq0 + b) * WPOOL + k0 + kk];
    __syncthreads();

    if (tid >= 120) return;
    const int ph = tid >> 3, j = tid & 7;
    const int proj = ph / 5, hh = ph % 5;
    const int e0 = (j < 7) ? 4 * j : 28;
    const bool quad = (j < 7);
    const float* Wm = (proj == 0) ? Wq : ((proj == 1) ? Wk : Wv);
    const float* wbase = Wm + (size_t)hh * WPOOL * 30 + (size_t)k0 * 30 + e0;
    const int hoff = quad ? 2 : 0;   // pair threads clamp hi-load in bounds

    float acc[BQT][4][4] = {};

#define LOADW(KK, LO, HI) do {                                   \
        int kc_ = (KK) < kn ? (KK) : kn - 1;                     \
        const float* p_ = wbase + (size_t)kc_ * 30;              \
        LO = *reinterpret_cast<const float2*>(p_);               \
        HI = *reinterpret_cast<const float2*>(p_ + hoff);        \
    } while (0)

#define DO_K(KK, LO, HI) do {                                    \
        float4 xa = xs[0][KK];                                   \
        float4 xb = xs[1][KK];                                   \
        acc[0][0][0] = fmaf(xa.x, LO.x, acc[0][0][0]);           \
        acc[0][1][0] = fmaf(xa.y, LO.x, acc[0][1][0]);           \
        acc[0][2][0] = fmaf(xa.z, LO.x, acc[0][2][0]);           \
        acc[0][3][0] = fmaf(xa.w, LO.x, acc[0][3][0]);           \
        acc[0][0][1] = fmaf(xa.x, LO.y, acc[0][0][1]);           \
        acc[0][1][1] = fmaf(xa.y, LO.y, acc[0][1][1]);           \
        acc[0][2][1] = fmaf(xa.z, LO.y, acc[0][2][1]);           \
        acc[0][3][1] = fmaf(xa.w, LO.y, acc[0][3][1]);           \
        acc[0][0][2] = fmaf(xa.x, HI.x, acc[0][0][2]);           \
        acc[0][1][2] = fmaf(xa.y, HI.x, acc[0][1][2]);           \
        acc[0][2][2] = fmaf(xa.z, HI.x, acc[0][2][2]);           \
        acc[0][3][2] = fmaf(xa.w, HI.x, acc[0][3][2]);           \
        acc[0][0][3] = fmaf(xa.x, HI.y, acc[0][0][3]);           \
        acc[0][1][3] = fmaf(xa.y, HI.y, acc[0][1][3]);           \
        acc[0][2][3] = fmaf(xa.z, HI.y, acc[0][2][3]);           \
        acc[0][3][3] = fmaf(xa.w, HI.y, acc[0][3][3]);           \
        acc[1][0][0] = fmaf(xb.x, LO.x, acc[1][0][0]);           \
        acc[1][1][0] = fmaf(xb.y, LO.x, acc[1][1][0]);           \
        acc[1][2][0] = fmaf(xb.z, LO.x, acc[1][2][0]);           \
        acc[1][3][0] = fmaf(xb.w, LO.x, acc[1][3][0]);           \
        acc[1][0][1] = fmaf(xb.x, LO.y, acc[1][0][1]);           \
        acc[1][1][1] = fmaf(xb.y, LO.y, acc[1][1][1]);           \
        acc[1][2][1] = fmaf(xb.z, LO.y, acc[1][2][1]);           \
        acc[1][3][1] = fmaf(xb.w, LO.y, acc[1][3][1]);           \
        acc[1][0][2] = fmaf(xb.x, HI.x, acc[1][0][2]);           \
        acc[1][1][2] = fmaf(xb.y, HI.x, acc[1][1][2]);           \
        acc[1][2][2] = fmaf(xb.z, HI.x, acc[1][2][2]);           \
        acc[1][3][2] = fmaf(xb.w, HI.x, acc[1][3][2]);           \
        acc[1][0][3] = fmaf(xb.x, HI.y, acc[1][0][3]);           \
        acc[1][1][3] = fmaf(xb.y, HI.y, acc[1][1][3]);           \
        acc[1][2][3] = fmaf(xb.z, HI.y, acc[1][2][3]);           \
        acc[1][3][3] = fmaf(xb.w, HI.y, acc[1][3][3]);           \
    } while (0)

    float2 s0l, s0h, s1l, s1h, s2l, s2h, s3l, s3h;
    LOADW(0, s0l, s0h);
    LOADW(1, s1l, s1h);
    LOADW(2, s2l, s2h);
    LOADW(3, s3l, s3h);

    int kk = 0;
    for (; kk + 4 <= kn; kk += 4) {
        { float2 lo = s0l, hi = s0h; LOADW(kk + 4, s0l, s0h); DO_K(kk + 0, lo, hi); }
        { float2 lo = s1l, hi = s1h; LOADW(kk + 5, s1l, s1h); DO_K(kk + 1, lo, hi); }
        { float2 lo = s2l, hi = s2h; LOADW(kk + 6, s2l, s2h); DO_K(kk + 2, lo, hi); }
        { float2 lo = s3l, hi = s3h; LOADW(kk + 7, s3l, s3h); DO_K(kk + 3, lo, hi); }
    }
    for (; kk < kn; ++kk) {   // tail (<=3 iters)
        float2 lo, hi;
        LOADW(kk, lo, hi);
        DO_K(kk, lo, hi);
    }
#undef LOADW
#undef DO_K

    // store partials: P[ks][b][s][n], n = proj*150 + hh*30 + e  (n0 even)
    const int n0 = proj * 150 + hh * 30 + e0;
    float* Pb = ws + WS_P + (size_t)ks * PSTRIDE;
#pragma unroll
    for (int b = 0; b < BQT; ++b) {
#pragma unroll
        for (int s = 0; s < 4; ++s) {
            float* p = Pb + (size_t)(bq0 + b) * 1800 + s * 450 + n0;
            reinterpret_cast<float2*>(p)[0] = make_float2(acc[b][s][0], acc[b][s][1]);
            if (quad)
                reinterpret_cast<float2*>(p + 2)[0] = make_float2(acc[b][s][2], acc[b][s][3]);
        }
    }
}

// -------- K3: attention (S=4 causal) + Wo + dense head ---------------------
__global__ __launch_bounds__(256) void k3_attn(const float* __restrict__ Wo,
    const float* __restrict__ d1w, const float* __restrict__ d1b,
    const float* __restrict__ d2w, const float* __restrict__ d2b,
    const float* __restrict__ d3w, const float* __restrict__ d3b,
    const float* __restrict__ ws, float* __restrict__ out)
{
    __shared__ float Qs[5][4][30], Ks2[5][4][30], Vs[5][4][30];
    __shared__ float sc[5][4][4];
    __shared__ float ob[4][150];
    __shared__ float hb[120], h1[10], h2[10];
    const int tid = threadIdx.x;
    const int b = blockIdx.x;
    const float* P = ws + WS_P + (size_t)b * 1800;

    for (int idx = tid; idx < 1800; idx += 256) {
        float val = 0.f;
#pragma unroll
        for (int ks = 0; ks < KSPLIT; ++ks)
            val += P[(size_t)ks * PSTRIDE + idx];   // lane-consecutive: coalesced
        int s = idx / 450, n = idx % 450;
        int proj = n / 150, hh = (n % 150) / 30, e = n % 30;
        if (proj == 0)      Qs[hh][s][e] = val;
        else if (proj == 1) Ks2[hh][s][e] = val;
        else                Vs[hh][s][e] = val;
    }
    __syncthreads();

    if (tid < 80) {
        int hh = tid >> 4, s = (tid >> 2) & 3, t = tid & 3;
        float a = 0.f;
        if (t <= s) {
            for (int e = 0; e < 30; ++e) a += Qs[hh][s][e] * Ks2[hh][t][e];
            a *= (1.0f / sqrtf(30.0f));
        }
        sc[hh][s][t] = a;
    }
    __syncthreads();

    if (tid < 20) {
        int hh = tid / 4, s = tid % 4;
        float m = -1e30f;
        for (int t = 0; t <= s; ++t) m = fmaxf(m, sc[hh][s][t]);
        float ex[4]; float den = 0.f;
        for (int t = 0; t <= s; ++t) { ex[t] = expf(sc[hh][s][t] - m); den += ex[t]; }
        for (int t = 0; t < 4; ++t) sc[hh][s][t] = (t <= s) ? ex[t] / den : 0.f;
    }
    __syncthreads();

    for (int idx = tid; idx < 600; idx += 256) {
        int s = idx / 150, j = idx % 150, hh = j / 30, e = j % 30;
        float a = 0.f;
        for (int t = 0; t < 4; ++t) a += sc[hh][s][t] * Vs[hh][t][e];
        ob[s][j] = a;
    }
    __syncthreads();

    if (tid < 120) {
        int s = tid / 30, e2 = tid % 30;
        float a = 0.f;
        for (int j = 0; j < 150; ++j) a += ob[s][j] * Wo[j * 30 + e2];
        hb[s * 30 + e2] = a;
    }
    __syncthreads();

    if (tid < 10) {
        float a = d1b[tid];
        for (int i = 0; i < 120; ++i) a += hb[i] * d1w[i * 10 + tid];
        h1[tid] = a > 0.f ? a : 0.2f * a;
    }
    __syncthreads();
    if (tid < 10) {
        float a = d2b[tid];
        for (int i = 0; i < 10; ++i) a += h1[i] * d2w[i * 10 + tid];
        h2[tid] = a > 0.f ? a : 0.2f * a;
    }
    __syncthreads();
    if (tid == 0) {
        float a = d3b[0];
        for (int i = 0; i < 10; ++i) a += h2[i] * d3w[i];
        out[b] = 1.f / (1.f + expf(-a));
    }
}

extern "C" void kernel_launch(void* const* d_in, const int* in_sizes, int n_in,
                              void* d_out, int out_size, void* d_ws, size_t ws_size,
                              hipStream_t stream)
{
    const int*   tokens = (const int*)d_in[0];
    const float* c1w = (const float*)d_in[1];
    const float* c1b = (const float*)d_in[2];
    const float* c2w = (const float*)d_in[3];
    const float* c2b = (const float*)d_in[4];
    const float* Wq  = (const float*)d_in[5];
    const float* Wk  = (const float*)d_in[6];
    const float* Wv  = (const float*)d_in[7];
    const float* Wo  = (const float*)d_in[8];
    const float* d1w = (const float*)d_in[9];
    const float* d1b = (const float*)d_in[10];
    const float* d2w = (const float*)d_in[11];
    const float* d2b = (const float*)d_in[12];
    const float* d3w = (const float*)d_in[13];
    const float* d3b = (const float*)d_in[14];
    float* ws = (float*)d_ws;
    float* out = (float*)d_out;

    k0_build<<<1, 256, 0, stream>>>(c1w, c1b, c2w, c2b, ws);
    k1_convpool<<<Bb * 16, 256, 0, stream>>>(tokens, c1w, c1b, c2w, c2b, ws);
    k2_qkv<<<(Bb / BQT) * KSPLIT, 128, 0, stream>>>(Wq, Wk, Wv, ws);
    k3_attn<<<Bb, 256, 0, stream>>>(Wo, d1w, d1b, d2w, d2b, d3w, d3b, ws, out);
}

// Round 4
// 226.783 us; speedup vs baseline: 2.7267x; 1.5174x over previous
//
#include <hip/hip_runtime.h>
#include <math.h>

#define Bb 256
#define Ll 20000
#define WPOOL 3999
#define HEADS 5
#define HDIM 30
#define KSPLIT 8
#define NQKV 450            // 3 proj * 5 heads * 30
#define PSTRIDE (NQKV*1024) // one k-split slice: 256 b * 4 s * 450 n floats
#define BQT 2               // batches per k2 block

// workspace layout (float offsets)
#define WS_F    0           // 360: F[t=0..4][d=0..17][i=0..3] (t=4 zero)
#define WS_BIAS 368         // 4: interior bias per row i
#define WS_G    384         // 900: G[p=t0*5+t1][j=0..8][i] = F[t0][2j]+F[t1][2j+1]
#define WS_FBL  1288        // 4*360: left-boundary tables, w=0..3
#define WS_FBR  2728        // 5*360: right-boundary tables, w'=0..4 (w=L-5+w')
#define WS_BBL  4528        // 4*4 left biases
#define WS_BBR  4544        // 5*4 right biases
#define WS_X    4608        // B*WPOOL*4 pooled features, [b][p][i]
#define WS_P    (WS_X + Bb*WPOOL*4)   // KSPLIT slices of qkv partials
// total floats: WS_P + 8*460800 = 7,785,984 (~29.7 MiB)

// -------- K0: build F, interior bias, pair table G, boundary tables --------
__global__ __launch_bounds__(256) void k0_build(const float* __restrict__ w1,
    const float* __restrict__ b1, const float* __restrict__ w2,
    const float* __restrict__ b2, float* __restrict__ ws)
{
    __shared__ float Fsh[360];
    const int tid = threadIdx.x;

    // F[t][d][i]: interior combined taps (kw2 unrestricted)
    for (int idx = tid; idx < 360; idx += 256) {
        int t = idx / 72, d = (idx / 4) % 18, i = idx % 4;
        float acc = 0.f;
        if (t < 4) {
            for (int kh = 0; kh < 4; ++kh) {
                int r = i + kh - 1;
                if (r < 0 || r > 3) continue;
                int kh1 = t - r + 1;
                if (kh1 < 0 || kh1 > 3) continue;
                for (int kw1 = 0; kw1 < 10; ++kw1) {
                    int kw2 = d - kw1;
                    if (kw2 < 0 || kw2 > 9) continue;
                    for (int c = 0; c < 5; ++c)
                        acc += w1[(kh1 * 10 + kw1) * 5 + c] * w2[(kh * 10 + kw2) * 5 + c];
                }
            }
        }
        Fsh[idx] = acc;
        ws[WS_F + idx] = acc;
    }
    // interior bias
    if (tid < 4) {
        int i = tid;
        float acc = b2[0];
        for (int kh = 0; kh < 4; ++kh) {
            int r = i + kh - 1;
            if (r < 0 || r > 3) continue;
            for (int kw2 = 0; kw2 < 10; ++kw2)
                for (int c = 0; c < 5; ++c)
                    acc += b1[c] * w2[(kh * 10 + kw2) * 5 + c];
        }
        ws[WS_BIAS + i] = acc;
    }
    __syncthreads();

    // G[p][j][i] = F[t0][2j][i] + F[t1][2j+1][i],  p = t0*5 + t1
    for (int idx = tid; idx < 900; idx += 256) {
        int p = idx / 36, j = (idx / 4) % 9, i = idx % 4;
        int t0 = p / 5, t1 = p % 5;
        ws[WS_G + idx] = Fsh[(t0 * 18 + 2 * j) * 4 + i] + Fsh[(t1 * 18 + 2 * j + 1) * 4 + i];
    }

    // boundary tap tables: wslot 0..3 = left w, 4..8 = right w'=wslot-4
    for (int idx = tid; idx < 9 * 360; idx += 256) {
        int wslot = idx / 360, rem = idx % 360;
        int t = rem / 72, d = (rem / 4) % 18, i = rem % 4;
        bool left = wslot < 4;
        int wloc = left ? wslot : wslot - 4;
        int kw2min = left ? 4 - wloc : 0;
        int kw2max = left ? 9 : 8 - wloc;
        float acc = 0.f;
        if (t < 4) {
            for (int kh = 0; kh < 4; ++kh) {
                int r = i + kh - 1;
                if (r < 0 || r > 3) continue;
                int kh1 = t - r + 1;
                if (kh1 < 0 || kh1 > 3) continue;
                for (int kw1 = 0; kw1 < 10; ++kw1) {
                    int kw2 = d - kw1;
                    if (kw2 < kw2min || kw2 > kw2max) continue;
                    for (int c = 0; c < 5; ++c)
                        acc += w1[(kh1 * 10 + kw1) * 5 + c] * w2[(kh * 10 + kw2) * 5 + c];
                }
            }
        }
        ws[(left ? WS_FBL + wloc * 360 : WS_FBR + wloc * 360) + rem] = acc;
    }
    // boundary biases
    if (tid < 36) {
        int wslot = tid / 4, i = tid % 4;
        bool left = wslot < 4;
        int wloc = left ? wslot : wslot - 4;
        int kw2min = left ? 4 - wloc : 0;
        int kw2max = left ? 9 : 8 - wloc;
        float acc = b2[0];
        for (int kh = 0; kh < 4; ++kh) {
            int r = i + kh - 1;
            if (r < 0 || r > 3) continue;
            for (int kw2 = kw2min; kw2 <= kw2max; ++kw2)
                for (int c = 0; c < 5; ++c)
                    acc += b1[c] * w2[(kh * 10 + kw2) * 5 + c];
        }
        ws[(left ? WS_BBL + wloc * 4 : WS_BBR + wloc * 4) + i] = acc;
    }
}

// -------- K1 v2: pair-table conv + in-register maxpool ---------------------
// block = (batch b, chunk of 250 pools). Thread t computes cols 5(p0+t)..+4
// in registers via 9 pair-table lookups/col, keeps the 5-col max; pool p =
// max(m5[p], m5[p+1]). Boundary cols (w<4, w>=L-5) use exact clipped tables
// read from global (2 threads per batch total).
__global__ __launch_bounds__(256) void k1_convpool(const int* __restrict__ tokens,
    const float* __restrict__ ws_c, float* __restrict__ ws)
{
    __shared__ int tok[1280];
    __shared__ float4 Gs[225];
    __shared__ float4 m5[256];
    __shared__ float4 biasS;

    const int tid = threadIdx.x;
    const int b = blockIdx.x >> 4;
    const int chunk = blockIdx.x & 15;
    const int p0 = chunk * 250;
    const int pcnt = min(250, WPOOL - p0);
    const int colBase = 5 * p0 - 8;      // token origin

    const float4* Gg = reinterpret_cast<const float4*>(ws_c + WS_G);
    for (int j = tid; j < 225; j += 256) Gs[j] = Gg[j];
    if (tid == 0) biasS = *reinterpret_cast<const float4*>(ws_c + WS_BIAS);
    const int* tb = tokens + (size_t)b * Ll;
    for (int j = tid; j < 1280; j += 256) {
        int u = colBase + j;
        tok[j] = (u >= 0 && u < Ll) ? tb[u] : 4;   // sentinel 4 -> zero rows
    }
    __syncthreads();

    if (tid <= pcnt) {
        const int W = 5 * (p0 + tid);            // first absolute col
        int tk[22];
#pragma unroll
        for (int m = 0; m < 22; ++m) tk[m] = tok[5 * tid + m];

        float4 mymax;
        const bool isLeft = (chunk == 0 && tid == 0);
        const bool isRight = (W + 4 >= Ll - 5);
        if (!isLeft && !isRight) {
            float4 bias4 = biasS;
            bool first = true;
#pragma unroll
            for (int c = 0; c < 5; ++c) {
                float a0 = bias4.x, a1 = bias4.y, a2 = bias4.z, a3 = bias4.w;
#pragma unroll
                for (int j = 0; j < 9; ++j) {
                    int pc = tk[c + 2 * j] * 5 + tk[c + 2 * j + 1];
                    float4 g = Gs[pc * 9 + j];
                    a0 += g.x; a1 += g.y; a2 += g.z; a3 += g.w;
                }
                if (first) { mymax = make_float4(a0, a1, a2, a3); first = false; }
                else {
                    mymax.x = fmaxf(mymax.x, a0); mymax.y = fmaxf(mymax.y, a1);
                    mymax.z = fmaxf(mymax.z, a2); mymax.w = fmaxf(mymax.w, a3);
                }
            }
        } else {
            // boundary thread: exact clipped tables from global (L2-hot, rare)
            bool first = true;
            for (int c = 0; c < 5; ++c) {
                int w = W + c;
                const float* T; const float* Bv;
                if (w < 4)            { T = ws_c + WS_FBL + w * 360;           Bv = ws_c + WS_BBL + 4 * w; }
                else if (w >= Ll - 5) { T = ws_c + WS_FBR + (w - (Ll - 5)) * 360; Bv = ws_c + WS_BBR + 4 * (w - (Ll - 5)); }
                else                  { T = ws_c + WS_F;                        Bv = ws_c + WS_BIAS; }
                float a0 = Bv[0], a1 = Bv[1], a2 = Bv[2], a3 = Bv[3];
                for (int d = 0; d < 18; ++d) {
                    const float* f = T + (size_t)(tk[c + d] * 18 + d) * 4;
                    a0 += f[0]; a1 += f[1]; a2 += f[2]; a3 += f[3];
                }
                if (first) { mymax = make_float4(a0, a1, a2, a3); first = false; }
                else {
                    mymax.x = fmaxf(mymax.x, a0); mymax.y = fmaxf(mymax.y, a1);
                    mymax.z = fmaxf(mymax.z, a2); mymax.w = fmaxf(mymax.w, a3);
                }
            }
        }
        m5[tid] = mymax;
    }
    __syncthreads();

    if (tid < pcnt) {
        float4 a = m5[tid], c = m5[tid + 1];
        a.x = fmaxf(a.x, c.x); a.y = fmaxf(a.y, c.y);
        a.z = fmaxf(a.z, c.z); a.w = fmaxf(a.w, c.w);
        reinterpret_cast<float4*>(ws + WS_X)[(size_t)b * WPOOL + p0 + tid] = a;
    }
}

// -------- K2: register-blocked qkv GEMM, 4-deep W prefetch ------------------
__global__ __launch_bounds__(128) void k2_qkv(const float* __restrict__ Wq,
    const float* __restrict__ Wk, const float* __restrict__ Wv,
    float* __restrict__ ws)
{
    __shared__ float4 xs[BQT][500];
    const int tid = threadIdx.x;
    const int ks = blockIdx.x & 7;
    const int bt = blockIdx.x >> 3;
    const int bq0 = bt * BQT;
    const int k0 = ks * 500;
    const int kn = min(500, WPOOL - k0);

    const float4* xg = reinterpret_cast<const float4*>(ws + WS_X);
#pragma unroll
    for (int b = 0; b < BQT; ++b)
        for (int kk = tid; kk < kn; kk += 128)
            xs[b][kk] = xg[(size_t)(bq0 + b) * WPOOL + k0 + kk];
    __syncthreads();

    if (tid >= 120) return;
    const int ph = tid >> 3, j = tid & 7;
    const int proj = ph / 5, hh = ph % 5;
    const int e0 = (j < 7) ? 4 * j : 28;
    const bool quad = (j < 7);
    const float* Wm = (proj == 0) ? Wq : ((proj == 1) ? Wk : Wv);
    const float* wbase = Wm + (size_t)hh * WPOOL * 30 + (size_t)k0 * 30 + e0;
    const int hoff = quad ? 2 : 0;

    float acc[BQT][4][4] = {};

#define LOADW(KK, LO, HI) do {                                   \
        int kc_ = (KK) < kn ? (KK) : kn - 1;                     \
        const float* p_ = wbase + (size_t)kc_ * 30;              \
        LO = *reinterpret_cast<const float2*>(p_);               \
        HI = *reinterpret_cast<const float2*>(p_ + hoff);        \
    } while (0)

#define DO_K(KK, LO, HI) do {                                    \
        float4 xa = xs[0][KK];                                   \
        float4 xb = xs[1][KK];                                   \
        acc[0][0][0] = fmaf(xa.x, LO.x, acc[0][0][0]);           \
        acc[0][1][0] = fmaf(xa.y, LO.x, acc[0][1][0]);           \
        acc[0][2][0] = fmaf(xa.z, LO.x, acc[0][2][0]);           \
        acc[0][3][0] = fmaf(xa.w, LO.x, acc[0][3][0]);           \
        acc[0][0][1] = fmaf(xa.x, LO.y, acc[0][0][1]);           \
        acc[0][1][1] = fmaf(xa.y, LO.y, acc[0][1][1]);           \
        acc[0][2][1] = fmaf(xa.z, LO.y, acc[0][2][1]);           \
        acc[0][3][1] = fmaf(xa.w, LO.y, acc[0][3][1]);           \
        acc[0][0][2] = fmaf(xa.x, HI.x, acc[0][0][2]);           \
        acc[0][1][2] = fmaf(xa.y, HI.x, acc[0][1][2]);           \
        acc[0][2][2] = fmaf(xa.z, HI.x, acc[0][2][2]);           \
        acc[0][3][2] = fmaf(xa.w, HI.x, acc[0][3][2]);           \
        acc[0][0][3] = fmaf(xa.x, HI.y, acc[0][0][3]);           \
        acc[0][1][3] = fmaf(xa.y, HI.y, acc[0][1][3]);           \
        acc[0][2][3] = fmaf(xa.z, HI.y, acc[0][2][3]);           \
        acc[0][3][3] = fmaf(xa.w, HI.y, acc[0][3][3]);           \
        acc[1][0][0] = fmaf(xb.x, LO.x, acc[1][0][0]);           \
        acc[1][1][0] = fmaf(xb.y, LO.x, acc[1][1][0]);           \
        acc[1][2][0] = fmaf(xb.z, LO.x, acc[1][2][0]);           \
        acc[1][3][0] = fmaf(xb.w, LO.x, acc[1][3][0]);           \
        acc[1][0][1] = fmaf(xb.x, LO.y, acc[1][0][1]);           \
        acc[1][1][1] = fmaf(xb.y, LO.y, acc[1][1][1]);           \
        acc[1][2][1] = fmaf(xb.z, LO.y, acc[1][2][1]);           \
        acc[1][3][1] = fmaf(xb.w, LO.y, acc[1][3][1]);           \
        acc[1][0][2] = fmaf(xb.x, HI.x, acc[1][0][2]);           \
        acc[1][1][2] = fmaf(xb.y, HI.x, acc[1][1][2]);           \
        acc[1][2][2] = fmaf(xb.z, HI.x, acc[1][2][2]);           \
        acc[1][3][2] = fmaf(xb.w, HI.x, acc[1][3][2]);           \
        acc[1][0][3] = fmaf(xb.x, HI.y, acc[1][0][3]);           \
        acc[1][1][3] = fmaf(xb.y, HI.y, acc[1][1][3]);           \
        acc[1][2][3] = fmaf(xb.z, HI.y, acc[1][2][3]);           \
        acc[1][3][3] = fmaf(xb.w, HI.y, acc[1][3][3]);           \
    } while (0)

    float2 s0l, s0h, s1l, s1h, s2l, s2h, s3l, s3h;
    LOADW(0, s0l, s0h);
    LOADW(1, s1l, s1h);
    LOADW(2, s2l, s2h);
    LOADW(3, s3l, s3h);

    int kk = 0;
    for (; kk + 4 <= kn; kk += 4) {
        { float2 lo = s0l, hi = s0h; LOADW(kk + 4, s0l, s0h); DO_K(kk + 0, lo, hi); }
        { float2 lo = s1l, hi = s1h; LOADW(kk + 5, s1l, s1h); DO_K(kk + 1, lo, hi); }
        { float2 lo = s2l, hi = s2h; LOADW(kk + 6, s2l, s2h); DO_K(kk + 2, lo, hi); }
        { float2 lo = s3l, hi = s3h; LOADW(kk + 7, s3l, s3h); DO_K(kk + 3, lo, hi); }
    }
    for (; kk < kn; ++kk) {
        float2 lo, hi;
        LOADW(kk, lo, hi);
        DO_K(kk, lo, hi);
    }
#undef LOADW
#undef DO_K

    const int n0 = proj * 150 + hh * 30 + e0;
    float* Pb = ws + WS_P + (size_t)ks * PSTRIDE;
#pragma unroll
    for (int b = 0; b < BQT; ++b) {
#pragma unroll
        for (int s = 0; s < 4; ++s) {
            float* p = Pb + (size_t)(bq0 + b) * 1800 + s * 450 + n0;
            reinterpret_cast<float2*>(p)[0] = make_float2(acc[b][s][0], acc[b][s][1]);
            if (quad)
                reinterpret_cast<float2*>(p + 2)[0] = make_float2(acc[b][s][2], acc[b][s][3]);
        }
    }
}

// -------- K3: attention (S=4 causal) + Wo + dense head ---------------------
__global__ __launch_bounds__(256) void k3_attn(const float* __restrict__ Wo,
    const float* __restrict__ d1w, const float* __restrict__ d1b,
    const float* __restrict__ d2w, const float* __restrict__ d2b,
    const float* __restrict__ d3w, const float* __restrict__ d3b,
    const float* __restrict__ ws, float* __restrict__ out)
{
    __shared__ float Qs[5][4][30], Ks2[5][4][30], Vs[5][4][30];
    __shared__ float sc[5][4][4];
    __shared__ float ob[4][150];
    __shared__ float hb[120], h1[10], h2[10];
    const int tid = threadIdx.x;
    const int b = blockIdx.x;
    const float* P = ws + WS_P + (size_t)b * 1800;

    for (int idx = tid; idx < 1800; idx += 256) {
        float val = 0.f;
#pragma unroll
        for (int ks = 0; ks < KSPLIT; ++ks)
            val += P[(size_t)ks * PSTRIDE + idx];
        int s = idx / 450, n = idx % 450;
        int proj = n / 150, hh = (n % 150) / 30, e = n % 30;
        if (proj == 0)      Qs[hh][s][e] = val;
        else if (proj == 1) Ks2[hh][s][e] = val;
        else                Vs[hh][s][e] = val;
    }
    __syncthreads();

    if (tid < 80) {
        int hh = tid >> 4, s = (tid >> 2) & 3, t = tid & 3;
        float a = 0.f;
        if (t <= s) {
            for (int e = 0; e < 30; ++e) a += Qs[hh][s][e] * Ks2[hh][t][e];
            a *= (1.0f / sqrtf(30.0f));
        }
        sc[hh][s][t] = a;
    }
    __syncthreads();

    if (tid < 20) {
        int hh = tid / 4, s = tid % 4;
        float m = -1e30f;
        for (int t = 0; t <= s; ++t) m = fmaxf(m, sc[hh][s][t]);
        float ex[4]; float den = 0.f;
        for (int t = 0; t <= s; ++t) { ex[t] = expf(sc[hh][s][t] - m); den += ex[t]; }
        for (int t = 0; t < 4; ++t) sc[hh][s][t] = (t <= s) ? ex[t] / den : 0.f;
    }
    __syncthreads();

    for (int idx = tid; idx < 600; idx += 256) {
        int s = idx / 150, j = idx % 150, hh = j / 30, e = j % 30;
        float a = 0.f;
        for (int t = 0; t < 4; ++t) a += sc[hh][s][t] * Vs[hh][t][e];
        ob[s][j] = a;
    }
    __syncthreads();

    if (tid < 120) {
        int s = tid / 30, e2 = tid % 30;
        float a = 0.f;
        for (int j = 0; j < 150; ++j) a += ob[s][j] * Wo[j * 30 + e2];
        hb[s * 30 + e2] = a;
    }
    __syncthreads();

    if (tid < 10) {
        float a = d1b[tid];
        for (int i = 0; i < 120; ++i) a += hb[i] * d1w[i * 10 + tid];
        h1[tid] = a > 0.f ? a : 0.2f * a;
    }
    __syncthreads();
    if (tid < 10) {
        float a = d2b[tid];
        for (int i = 0; i < 10; ++i) a += h1[i] * d2w[i * 10 + tid];
        h2[tid] = a > 0.f ? a : 0.2f * a;
    }
    __syncthreads();
    if (tid == 0) {
        float a = d3b[0];
        for (int i = 0; i < 10; ++i) a += h2[i] * d3w[i];
        out[b] = 1.f / (1.f + expf(-a));
    }
}

extern "C" void kernel_launch(void* const* d_in, const int* in_sizes, int n_in,
                              void* d_out, int out_size, void* d_ws, size_t ws_size,
                              hipStream_t stream)
{
    const int*   tokens = (const int*)d_in[0];
    const float* c1w = (const float*)d_in[1];
    const float* c1b = (const float*)d_in[2];
    const float* c2w = (const float*)d_in[3];
    const float* c2b = (const float*)d_in[4];
    const float* Wq  = (const float*)d_in[5];
    const float* Wk  = (const float*)d_in[6];
    const float* Wv  = (const float*)d_in[7];
    const float* Wo  = (const float*)d_in[8];
    const float* d1w = (const float*)d_in[9];
    const float* d1b = (const float*)d_in[10];
    const float* d2w = (const float*)d_in[11];
    const float* d2b = (const float*)d_in[12];
    const float* d3w = (const float*)d_in[13];
    const float* d3b = (const float*)d_in[14];
    float* ws = (float*)d_ws;
    float* out = (float*)d_out;

    k0_build<<<1, 256, 0, stream>>>(c1w, c1b, c2w, c2b, ws);
    k1_convpool<<<Bb * 16, 256, 0, stream>>>(tokens, ws, ws);
    k2_qkv<<<(Bb / BQT) * KSPLIT, 128, 0, stream>>>(Wq, Wk, Wv, ws);
    k3_attn<<<Bb, 256, 0, stream>>>(Wo, d1w, d1b, d2w, d2b, d3w, d3b, ws, out);
}